// Round 7
// baseline (498.492 us; speedup 1.0000x reference)
//
#include <hip/hip_runtime.h>
#include <hip/hip_bf16.h>
#include <math.h>

#define B_  2
#define T_  2048
#define D_  1024
#define H_  16
#define DK_ 64
#define FF_ 4096
#define BT_ (B_*T_)

typedef __attribute__((ext_vector_type(8))) short bf16x8;
typedef __attribute__((ext_vector_type(4))) float f32x4;

__device__ __forceinline__ ushort f2bf(float f) {
    __hip_bfloat16 h = __float2bfloat16(f);
    return *reinterpret_cast<ushort*>(&h);
}
__device__ __forceinline__ float bf2f(ushort u) {
    __hip_bfloat16 h;
    *reinterpret_cast<ushort*>(&h) = u;
    return __bfloat162float(h);
}

// async global->LDS, 16B per lane. LDS dest must be wave-uniform base + lane*16.
__device__ __forceinline__ void g2l16(const ushort* g, ushort* l) {
    __builtin_amdgcn_global_load_lds(
        (const __attribute__((address_space(1))) void*)g,
        (__attribute__((address_space(3))) void*)l, 16, 0, 0);
}

// ---------------------------------------------------------------------------
// f32 -> bf16 elementwise (vectorized, n multiple of 1024)
// ---------------------------------------------------------------------------
__global__ __launch_bounds__(256) void cvt_bf16_kernel(
    const float* __restrict__ in, ushort* __restrict__ out, int n)
{
    int i = (blockIdx.x * 256 + threadIdx.x) * 4;
    if (i >= n) return;
    float4 v = *(const float4*)(in + i);
    ushort4 o;
    o.x = f2bf(v.x); o.y = f2bf(v.y); o.z = f2bf(v.z); o.w = f2bf(v.w);
    *(ushort4*)(out + i) = o;
}

// ---------------------------------------------------------------------------
// transpose + convert: in f32 [K][N] -> out bf16 [N][K]; batched over z.
// ---------------------------------------------------------------------------
__global__ __launch_bounds__(256) void transpose_bf16_kernel(
    const float* __restrict__ in, ushort* __restrict__ out,
    int K, int N, long in_bstride, long out_bstride)
{
    __shared__ float t[32][33];
    const float* ib = in + (size_t)blockIdx.z * in_bstride;
    ushort* ob = out + (size_t)blockIdx.z * out_bstride;
    int n0 = blockIdx.x * 32, k0 = blockIdx.y * 32;
    int tid = threadIdx.x;
    int r = tid >> 3, c4 = (tid & 7) * 4;
    float4 v = *(const float4*)(ib + (size_t)(k0 + r) * N + n0 + c4);
    t[r][c4] = v.x; t[r][c4+1] = v.y; t[r][c4+2] = v.z; t[r][c4+3] = v.w;
    __syncthreads();
    int n = tid >> 3, kc = (tid & 7) * 4;
    ushort4 o;
    o.x = f2bf(t[kc+0][n]); o.y = f2bf(t[kc+1][n]);
    o.z = f2bf(t[kc+2][n]); o.w = f2bf(t[kc+3][n]);
    *(ushort4*)(ob + (size_t)(n0 + n) * K + k0 + kc) = o;
}

// ---------------------------------------------------------------------------
// 256x256-tile NT GEMM, bf16 MFMA, BK=32, 512 threads (8 waves, 2Mx4N,
// per-wave 128x64). Minimum-2-phase (T3 recipe): per K-tile
//   STAGE(buf^1, t+1) ; ds_read frags from buf[cur] ; 32 MFMA ;
//   __syncthreads() (vmcnt+lgkm drain publishes stage, protects WAR) ; cur^=1
// LDS 64KB double-buffered -> 2 blocks/CU. XCD swizzle. Split-K via blockIdx.z.
// ---------------------------------------------------------------------------
template<int OUT_BF16>
__global__ __launch_bounds__(512) void gemm256_kernel(
    const ushort* __restrict__ A, int lda,
    const ushort* __restrict__ Bt, int ldb,
    void* __restrict__ C, int ldc, int K,
    const float* __restrict__ bias,
    const float* __restrict__ resid, int relu,
    long aZoff, long bZoff, long cZoff)
{
    __shared__ __attribute__((aligned(16))) ushort As[2][4][256][8];
    __shared__ __attribute__((aligned(16))) ushort Bs[2][4][256][8];

    A  += (size_t)blockIdx.z * aZoff;
    Bt += (size_t)blockIdx.z * bZoff;
    char* Cb = (char*)C + (size_t)blockIdx.z * cZoff * (OUT_BF16 ? 2 : 4);

    // XCD swizzle over x,y (nwg per z-slice must be %8==0 -- true here)
    int nwg  = gridDim.x * gridDim.y;
    int orig = blockIdx.y * gridDim.x + blockIdx.x;
    int work = (orig & 7) * (nwg >> 3) + (orig >> 3);
    int bx = work % gridDim.x, by = work / gridDim.x;

    int row0 = by * 256, col0 = bx * 256;
    int tid = threadIdx.x;
    int l = tid & 63;
    int w = tid >> 6;
    int wr = (w >> 2) * 128, wc = (w & 3) * 64;

    // staging coords: m const per thread, kc = kc0 + 2p (p=0,1)
    int m = tid & 255, kc0 = tid >> 8;   // kc0 in {0,1}
    const ushort* gA = A  + (size_t)(row0 + m) * lda + kc0 * 8;
    const ushort* gB = Bt + (size_t)(col0 + m) * ldb + kc0 * 8;

    f32x4 acc[8][4];
    #pragma unroll
    for (int i = 0; i < 8; ++i)
        #pragma unroll
        for (int j = 0; j < 4; ++j) acc[i][j] = (f32x4){0.f, 0.f, 0.f, 0.f};

    const int NT = K >> 5;

    // prologue: stage tile 0 into buf 0
    #pragma unroll
    for (int p = 0; p < 2; ++p) {
        g2l16(gA + p*16, &As[0][kc0 + 2*p][m][0]);
        g2l16(gB + p*16, &Bs[0][kc0 + 2*p][m][0]);
    }
    __syncthreads();

    int cur = 0;
    for (int t = 0; t < NT; ++t) {
        if (t + 1 < NT) {               // stage next tile into buf^1 (issue early)
            int k0 = (t + 1) << 5;
            #pragma unroll
            for (int p = 0; p < 2; ++p) {
                g2l16(gA + k0 + p*16, &As[cur ^ 1][kc0 + 2*p][m][0]);
                g2l16(gB + k0 + p*16, &Bs[cur ^ 1][kc0 + 2*p][m][0]);
            }
        }
        int kc = l >> 4;                // 0..3
        bf16x8 bfr[4];
        #pragma unroll
        for (int j = 0; j < 4; ++j)
            bfr[j] = *(const bf16x8*)&Bs[cur][kc][wc + j*16 + (l & 15)][0];
        #pragma unroll
        for (int i = 0; i < 8; ++i) {
            bf16x8 a = *(const bf16x8*)&As[cur][kc][wr + i*16 + (l & 15)][0];
            #pragma unroll
            for (int j = 0; j < 4; ++j)
                acc[i][j] = __builtin_amdgcn_mfma_f32_16x16x32_bf16(
                    a, bfr[j], acc[i][j], 0, 0, 0);
        }
        __syncthreads();                // single drain: publish stage + WAR
        cur ^= 1;
    }

    #pragma unroll
    for (int i = 0; i < 8; ++i) {
        int rbase = row0 + wr + i*16 + (l >> 4) * 4;
        #pragma unroll
        for (int j = 0; j < 4; ++j) {
            int col = col0 + wc + j*16 + (l & 15);
            float bv = bias ? bias[col] : 0.f;
            #pragma unroll
            for (int r = 0; r < 4; ++r) {
                int row = rbase + r;
                float val = acc[i][j][r] + bv;
                if (resid) val += resid[(size_t)row * ldc + col];
                if (relu)  val = fmaxf(val, 0.f);
                if (OUT_BF16) ((ushort*)Cb)[(size_t)row * ldc + col] = f2bf(val);
                else          ((float*)Cb)[(size_t)row * ldc + col]  = val;
            }
        }
    }
}

// ---------------------------------------------------------------------------
// 128x128 NT GEMM (Wo: N=1024 -> 256 blocks). Minimum-2-phase, BK=32,
// 32KB dbuf LDS. Same single-barrier structure.
// ---------------------------------------------------------------------------
template<int OUT_BF16>
__global__ __launch_bounds__(256) void gemm_nt_kernel(
    const ushort* __restrict__ A, int lda,
    const ushort* __restrict__ Bt, int ldb,
    void* __restrict__ C, int ldc, int K,
    const float* __restrict__ bias,
    const float* __restrict__ resid, int relu)
{
    __shared__ __attribute__((aligned(16))) ushort As[2][4][128][8];
    __shared__ __attribute__((aligned(16))) ushort Bs[2][4][128][8];

    int nwg  = gridDim.x * gridDim.y;
    int orig = blockIdx.y * gridDim.x + blockIdx.x;
    int work = (orig & 7) * (nwg >> 3) + (orig >> 3);
    int bx = work % gridDim.x, by = work / gridDim.x;

    int row0 = by * 128, col0 = bx * 128;
    int tid = threadIdx.x;
    int w = tid >> 6, l = tid & 63;
    int wr = (w >> 1) * 64, wc = (w & 1) * 64;

    int m0 = tid & 127, kc0 = tid >> 7;
    int m1 = (tid + 256) & 127, kc1 = (tid + 256) >> 7;
    const ushort* ga0 = A  + (size_t)(row0 + m0) * lda + kc0 * 8;
    const ushort* ga1 = A  + (size_t)(row0 + m1) * lda + kc1 * 8;
    const ushort* gb0 = Bt + (size_t)(col0 + m0) * ldb + kc0 * 8;
    const ushort* gb1 = Bt + (size_t)(col0 + m1) * ldb + kc1 * 8;

    f32x4 acc[4][4];
    #pragma unroll
    for (int i = 0; i < 4; ++i)
        #pragma unroll
        for (int j = 0; j < 4; ++j) acc[i][j] = (f32x4){0.f, 0.f, 0.f, 0.f};

    const int NT = K >> 5;
    g2l16(ga0, &As[0][kc0][m0][0]);
    g2l16(ga1, &As[0][kc1][m1][0]);
    g2l16(gb0, &Bs[0][kc0][m0][0]);
    g2l16(gb1, &Bs[0][kc1][m1][0]);
    __syncthreads();

    int cur = 0;
    for (int t = 0; t < NT; ++t) {
        if (t + 1 < NT) {
            int k0 = (t + 1) << 5;
            g2l16(ga0 + k0, &As[cur ^ 1][kc0][m0][0]);
            g2l16(ga1 + k0, &As[cur ^ 1][kc1][m1][0]);
            g2l16(gb0 + k0, &Bs[cur ^ 1][kc0][m0][0]);
            g2l16(gb1 + k0, &Bs[cur ^ 1][kc1][m1][0]);
        }
        int kc = l >> 4;
        bf16x8 af[4], bfr[4];
        #pragma unroll
        for (int i = 0; i < 4; ++i)
            af[i] = *(const bf16x8*)&As[cur][kc][wr + i*16 + (l & 15)][0];
        #pragma unroll
        for (int j = 0; j < 4; ++j)
            bfr[j] = *(const bf16x8*)&Bs[cur][kc][wc + j*16 + (l & 15)][0];
        #pragma unroll
        for (int i = 0; i < 4; ++i)
            #pragma unroll
            for (int j = 0; j < 4; ++j)
                acc[i][j] = __builtin_amdgcn_mfma_f32_16x16x32_bf16(
                    af[i], bfr[j], acc[i][j], 0, 0, 0);
        __syncthreads();
        cur ^= 1;
    }

    #pragma unroll
    for (int i = 0; i < 4; ++i) {
        int rbase = row0 + wr + i*16 + (l >> 4) * 4;
        #pragma unroll
        for (int j = 0; j < 4; ++j) {
            int col = col0 + wc + j*16 + (l & 15);
            float bv = bias ? bias[col] : 0.f;
            #pragma unroll
            for (int r = 0; r < 4; ++r) {
                int row = rbase + r;
                float val = acc[i][j][r] + bv;
                if (resid) val += resid[(size_t)row * ldc + col];
                if (relu)  val = fmaxf(val, 0.f);
                if (OUT_BF16) ((ushort*)C)[(size_t)row * ldc + col] = f2bf(val);
                else          ((float*)C)[(size_t)row * ldc + col]  = val;
            }
        }
    }
}

// ---------------------------------------------------------------------------
// colsum[s] = sum_q exp(q·k/8).  grid (T/128, B*H), 256 thr.
// qkv packed [bt][3072]: q at col 0, k at 1024, v at 2048 (+h*64).
// ---------------------------------------------------------------------------
__global__ __launch_bounds__(256) void csum_kernel(
    const ushort* __restrict__ qkv, float* __restrict__ col_sum)
{
    int bh = blockIdx.y, b = bh >> 4, h = bh & 15;
    int s0 = blockIdx.x * 128;
    const ushort* qb = qkv + (size_t)b * T_ * 3072 + h * 64;
    const ushort* kb = qb + 1024;
    __shared__ __attribute__((aligned(16))) ushort Ks[8][128][8];
    __shared__ __attribute__((aligned(16))) ushort Qs[8][64][8];
    int tid = threadIdx.x, w = tid >> 6, l = tid & 63;
    int scol = w * 32;

    #pragma unroll
    for (int p = 0; p < 4; ++p) {
        int idx = tid + p * 256;
        int s = idx & 127, kc = idx >> 7;
        *(uint4*)&Ks[kc][s][0] =
            *(const uint4*)(kb + (size_t)(s0 + s) * 3072 + kc * 8);
    }
    float cs[2] = {0.f, 0.f};
    for (int qt = 0; qt < T_ / 64; ++qt) {
        __syncthreads();
        #pragma unroll
        for (int p = 0; p < 2; ++p) {
            int idx = tid + p * 256;
            int qq = idx & 63, kc = idx >> 6;
            *(uint4*)&Qs[kc][qq][0] =
                *(const uint4*)(qb + (size_t)(qt*64 + qq) * 3072 + kc * 8);
        }
        __syncthreads();
        bf16x8 af[4][2], bfr[2][2];
        #pragma unroll
        for (int qi = 0; qi < 4; ++qi)
            #pragma unroll
            for (int ks = 0; ks < 2; ++ks)
                af[qi][ks] = *(const bf16x8*)&Qs[ks*4 + (l>>4)][qi*16 + (l & 15)][0];
        #pragma unroll
        for (int sj = 0; sj < 2; ++sj)
            #pragma unroll
            for (int ks = 0; ks < 2; ++ks)
                bfr[sj][ks] = *(const bf16x8*)&Ks[ks*4 + (l>>4)][scol + sj*16 + (l & 15)][0];
        #pragma unroll
        for (int qi = 0; qi < 4; ++qi)
            #pragma unroll
            for (int sj = 0; sj < 2; ++sj) {
                f32x4 d = (f32x4){0.f, 0.f, 0.f, 0.f};
                #pragma unroll
                for (int ks = 0; ks < 2; ++ks)
                    d = __builtin_amdgcn_mfma_f32_16x16x32_bf16(
                        af[qi][ks], bfr[sj][ks], d, 0, 0, 0);
                cs[sj] += __expf(d[0]*0.125f) + __expf(d[1]*0.125f)
                        + __expf(d[2]*0.125f) + __expf(d[3]*0.125f);
            }
    }
    #pragma unroll
    for (int sj = 0; sj < 2; ++sj) {
        float v = cs[sj];
        v += __shfl_down(v, 32, 64);
        v += __shfl_down(v, 16, 64);
        if (l < 16)
            col_sum[(size_t)bh * T_ + s0 + scol + sj*16 + l] = v;
    }
}

// ---------------------------------------------------------------------------
// vt[bh][dv][s] = v[bh][s][dv] / colsum[bh][s]   (bf16, transposed V)
// ---------------------------------------------------------------------------
__global__ __launch_bounds__(256) void vscale_kernel(
    const ushort* __restrict__ qkv, const float* __restrict__ col_sum,
    ushort* __restrict__ vt)
{
    int bh = blockIdx.y, b = bh >> 4, h = bh & 15;
    int s0 = blockIdx.x * 64;
    const ushort* vb = qkv + (size_t)b * T_ * 3072 + 2048 + h * 64;
    __shared__ float t[64][65];
    int tid = threadIdx.x;
    #pragma unroll
    for (int p = 0; p < 2; ++p) {
        int idx = tid + p * 256;
        int s = idx >> 3, c0 = (idx & 7) * 8;
        uint4 raw = *(const uint4*)(vb + (size_t)(s0 + s) * 3072 + c0);
        float rc = 1.0f / col_sum[(size_t)bh * T_ + s0 + s];
        ushort* u = (ushort*)&raw;
        #pragma unroll
        for (int i = 0; i < 8; ++i) t[s][c0 + i] = bf2f(u[i]) * rc;
    }
    __syncthreads();
    #pragma unroll
    for (int p = 0; p < 2; ++p) {
        int idx = tid + p * 256;
        int dv = idx >> 3, sc = (idx & 7) * 8;
        ushort o[8];
        #pragma unroll
        for (int i = 0; i < 8; ++i) o[i] = f2bf(t[sc + i][dv]);
        *(uint4*)(vt + ((size_t)bh * 64 + dv) * T_ + s0 + sc) = *(uint4*)o;
    }
}

// ---------------------------------------------------------------------------
// PV: O[q][dv] = sum_s exp(q·k/8) * vt[dv][s].  grid (T/64, B*H), 256 thr.
// ---------------------------------------------------------------------------
__global__ __launch_bounds__(256) void attn_pv_kernel(
    const ushort* __restrict__ qkv, const ushort* __restrict__ vt,
    ushort* __restrict__ attn_o)
{
    int bh = blockIdx.y, b = bh >> 4, h = bh & 15;
    int q0 = blockIdx.x * 64;
    const ushort* qb = qkv + (size_t)b * T_ * 3072 + h * 64;
    const ushort* kb = qb + 1024;
    const ushort* vtb = vt + (size_t)bh * 64 * T_;
    __shared__ __attribute__((aligned(16))) ushort Qs[8][64][8];
    __shared__ __attribute__((aligned(16))) ushort Ks[8][64][8];
    __shared__ __attribute__((aligned(16))) ushort Vs[8][64][8];
    __shared__ __attribute__((aligned(16))) ushort Es[8][64][8];
    int tid = threadIdx.x, w = tid >> 6, l = tid & 63;
    int qw = w * 16;

    #pragma unroll
    for (int p = 0; p < 2; ++p) {
        int idx = tid + p * 256;
        int qq = idx & 63, kc = idx >> 6;
        *(uint4*)&Qs[kc][qq][0] =
            *(const uint4*)(qb + (size_t)(q0 + qq) * 3072 + kc * 8);
    }
    __syncthreads();
    bf16x8 qf[2];
    #pragma unroll
    for (int ks = 0; ks < 2; ++ks)
        qf[ks] = *(const bf16x8*)&Qs[ks*4 + (l>>4)][qw + (l & 15)][0];

    f32x4 oacc[4];
    #pragma unroll
    for (int j = 0; j < 4; ++j) oacc[j] = (f32x4){0.f, 0.f, 0.f, 0.f};

    for (int st = 0; st < T_ / 64; ++st) {
        int s0 = st * 64;
        __syncthreads();
        #pragma unroll
        for (int p = 0; p < 2; ++p) {
            int idx = tid + p * 256;
            int rr = idx & 63, kc = idx >> 6;
            *(uint4*)&Ks[kc][rr][0] =
                *(const uint4*)(kb + (size_t)(s0 + rr) * 3072 + kc * 8);
            *(uint4*)&Vs[kc][rr][0] =
                *(const uint4*)(vtb + (size_t)rr * T_ + s0 + kc * 8);
        }
        __syncthreads();
        #pragma unroll
        for (int sj = 0; sj < 4; ++sj) {
            f32x4 d = (f32x4){0.f, 0.f, 0.f, 0.f};
            #pragma unroll
            for (int ks = 0; ks < 2; ++ks) {
                bf16x8 kf = *(const bf16x8*)&Ks[ks*4 + (l>>4)][sj*16 + (l & 15)][0];
                d = __builtin_amdgcn_mfma_f32_16x16x32_bf16(qf[ks], kf, d, 0, 0, 0);
            }
            #pragma unroll
            for (int r = 0; r < 4; ++r) {
                int qq = qw + (l>>4)*4 + r;
                int ss = sj*16 + (l & 15);
                Es[ss >> 3][qq][ss & 7] = f2bf(__expf(d[r] * 0.125f));
            }
        }
        bf16x8 ef[2];
        #pragma unroll
        for (int ks = 0; ks < 2; ++ks)
            ef[ks] = *(const bf16x8*)&Es[ks*4 + (l>>4)][qw + (l & 15)][0];
        #pragma unroll
        for (int j = 0; j < 4; ++j)
            #pragma unroll
            for (int ks = 0; ks < 2; ++ks) {
                bf16x8 vf = *(const bf16x8*)&Vs[ks*4 + (l>>4)][j*16 + (l & 15)][0];
                oacc[j] = __builtin_amdgcn_mfma_f32_16x16x32_bf16(ef[ks], vf, oacc[j], 0, 0, 0);
            }
    }
    #pragma unroll
    for (int j = 0; j < 4; ++j)
        #pragma unroll
        for (int r = 0; r < 4; ++r) {
            int qq = q0 + qw + (l>>4)*4 + r;
            int dv = j*16 + (l & 15);
            attn_o[(size_t)(b*T_ + qq) * 1024 + h*64 + dv] = f2bf(oacc[j][r]);
        }
}

// ---------------------------------------------------------------------------
// mean/std norm (Bessel), optional bf16 side-output.
// ---------------------------------------------------------------------------
__device__ __forceinline__ float block_reduce_sum_256(float v, float* tmp)
{
    #pragma unroll
    for (int off = 32; off; off >>= 1) v += __shfl_down(v, off, 64);
    int lane = threadIdx.x & 63, w = threadIdx.x >> 6;
    __syncthreads();
    if (lane == 0) tmp[w] = v;
    __syncthreads();
    return tmp[0] + tmp[1] + tmp[2] + tmp[3];
}

__global__ __launch_bounds__(256) void norm_kernel(
    const float* __restrict__ in, float* __restrict__ outf,
    ushort* __restrict__ outb)
{
    __shared__ float tmp[4];
    int row = blockIdx.x;
    const float* r = in + (size_t)row * D_;
    int tid = threadIdx.x;
    float vals[4];
    #pragma unroll
    for (int i = 0; i < 4; ++i) vals[i] = r[tid + i*256];
    float s = vals[0] + vals[1] + vals[2] + vals[3];
    s = block_reduce_sum_256(s, tmp);
    float m = s * (1.0f / (float)D_);
    float sq = 0.f;
    #pragma unroll
    for (int i = 0; i < 4; ++i) { float c = vals[i] - m; sq += c * c; }
    sq = block_reduce_sum_256(sq, tmp);
    float rs = rsqrtf(sq * (1.0f / (float)(D_ - 1)));
    #pragma unroll
    for (int i = 0; i < 4; ++i) {
        float o = (vals[i] - m) * rs;
        outf[(size_t)row * D_ + tid + i*256] = o;
        if (outb) outb[(size_t)row * D_ + tid + i*256] = f2bf(o);
    }
}

// ---------------------------------------------------------------------------
// norm2 fused: y = sum_{z<8} parts[z] (bf16 partials) + b2 + resid,
// then mean/std norm -> out f32.
// ---------------------------------------------------------------------------
__global__ __launch_bounds__(256) void norm2_fused_kernel(
    const ushort* __restrict__ parts, long zoff,
    const float* __restrict__ b2, const float* __restrict__ resid,
    float* __restrict__ outp)
{
    __shared__ float tmp[4];
    int row = blockIdx.x;
    int tid = threadIdx.x;
    int c0 = tid * 4;
    size_t idx = (size_t)row * D_ + c0;
    float vals[4] = {0.f, 0.f, 0.f, 0.f};
    #pragma unroll
    for (int z = 0; z < 8; ++z) {
        ushort4 p = *(const ushort4*)&parts[idx + (size_t)z * zoff];
        vals[0] += bf2f(p.x); vals[1] += bf2f(p.y);
        vals[2] += bf2f(p.z); vals[3] += bf2f(p.w);
    }
    float4 rv = *(const float4*)&resid[idx];
    float4 bv = *(const float4*)&b2[c0];
    vals[0] += bv.x + rv.x; vals[1] += bv.y + rv.y;
    vals[2] += bv.z + rv.z; vals[3] += bv.w + rv.w;
    float s = vals[0] + vals[1] + vals[2] + vals[3];
    s = block_reduce_sum_256(s, tmp);
    float m = s * (1.0f / (float)D_);
    float sq = 0.f;
    #pragma unroll
    for (int i = 0; i < 4; ++i) { float c = vals[i] - m; sq += c * c; }
    sq = block_reduce_sum_256(sq, tmp);
    float rs = rsqrtf(sq * (1.0f / (float)(D_ - 1)));
    float4 o;
    o.x = (vals[0] - m) * rs; o.y = (vals[1] - m) * rs;
    o.z = (vals[2] - m) * rs; o.w = (vals[3] - m) * rs;
    *(float4*)&outp[idx] = o;
}

// ---------------------------------------------------------------------------
extern "C" void kernel_launch(void* const* d_in, const int* in_sizes, int n_in,
                              void* d_out, int out_size, void* d_ws, size_t ws_size,
                              hipStream_t stream)
{
    const float* x  = (const float*)d_in[0];
    const float* Wq = (const float*)d_in[1];
    const float* Wk = (const float*)d_in[2];
    const float* Wv = (const float*)d_in[3];
    const float* Wo = (const float*)d_in[4];
    const float* W1 = (const float*)d_in[5];
    const float* b1 = (const float*)d_in[6];
    const float* W2 = (const float*)d_in[7];
    const float* b2 = (const float*)d_in[8];
    float* out = (float*)d_out;

    const size_t MB = (size_t)1 << 20;
    char* base = (char*)d_ws;
    // lifetimes (peak 120MB at W2):
    ushort* qkv    = (ushort*)(base +   0*MB);  // 24MB  [QKV..PV]
    ushort* hid    = (ushort*)(base +   0*MB);  // 32MB  [W1..W2]     (reuses qkv+xb)
    ushort* xb     = (ushort*)(base +  24*MB);  //  8MB  [cvt..QKV]
    ushort* W2t    = (ushort*)(base +  32*MB);  //  8MB  [cvt..W2]
    ushort* Wqkvt  = (ushort*)(base +  40*MB);  //  6MB  [cvt..QKV]
    ushort* wpart  = (ushort*)(base +  40*MB);  // 64MB  [W2..norm2]  (reuses 40-104)
    ushort* vt     = (ushort*)(base +  46*MB);  //  8MB  [vscale..PV]
    float*  csum   = (float*) (base +  54*MB);  // .25MB [csum..vscale]
    ushort* Wot    = (ushort*)(base +  55*MB);  //  2MB  [cvt..Wo]
    ushort* W1t    = (ushort*)(base +  57*MB);  //  8MB  [cvt..W1]
    ushort* attn_o = (ushort*)(base +  65*MB);  //  8MB  [PV..Wo]
    float*  oproj  = (float*) (base +  73*MB);  // 16MB  [Wo..norm1]
    ushort* out1b  = (ushort*)(base +  89*MB);  //  8MB  [norm1..W1]
    float*  out1f  = (float*) (base + 104*MB);  // 16MB  [norm1..norm2]

    // 1. converts / transposes
    cvt_bf16_kernel<<<dim3(BT_*D_/1024), 256, 0, stream>>>(x, xb, BT_*D_);
    transpose_bf16_kernel<<<dim3(2, 32, 16), 256, 0, stream>>>(
        Wq, Wqkvt + 0*1048576, 1024, 64, 65536, 65536);
    transpose_bf16_kernel<<<dim3(2, 32, 16), 256, 0, stream>>>(
        Wk, Wqkvt + 1*1048576, 1024, 64, 65536, 65536);
    transpose_bf16_kernel<<<dim3(2, 32, 16), 256, 0, stream>>>(
        Wv, Wqkvt + 2*1048576, 1024, 64, 65536, 65536);
    transpose_bf16_kernel<<<dim3(32, 32, 1), 256, 0, stream>>>(
        Wo, Wot, 1024, 1024, 0, 0);
    transpose_bf16_kernel<<<dim3(128, 32, 1), 256, 0, stream>>>(
        W1, W1t, 1024, 4096, 0, 0);
    transpose_bf16_kernel<<<dim3(32, 128, 1), 256, 0, stream>>>(
        W2, W2t, 4096, 1024, 0, 0);

    // 2. QKV: [4096,1024] @ [3072,1024]^T -> qkv bf16 [4096,3072]
    gemm256_kernel<1><<<dim3(3072/256, 4096/256, 1), 512, 0, stream>>>(
        xb, 1024, Wqkvt, 1024, qkv, 3072, 1024, nullptr, nullptr, 0, 0, 0, 0);
    // 3. column sums of exp(scores)
    csum_kernel<<<dim3(T_/128, B_*H_), 256, 0, stream>>>(qkv, csum);
    // 4. vt = (v/colsum)^T
    vscale_kernel<<<dim3(T_/64, B_*H_), 256, 0, stream>>>(qkv, csum, vt);
    // 5. PV
    attn_pv_kernel<<<dim3(T_/64, B_*H_), 256, 0, stream>>>(qkv, vt, attn_o);
    // 6. Wo projection + residual x -> oproj f32 (128^2 tile: 256 blocks)
    gemm_nt_kernel<0><<<dim3(1024/128, 4096/128), 256, 0, stream>>>(
        attn_o, 1024, Wot, 1024, oproj, 1024, 1024, nullptr, x, 0);
    // 7. norm1 -> out1f (f32) + out1b (bf16)
    norm_kernel<<<dim3(BT_), 256, 0, stream>>>(oproj, out1f, out1b);
    // 8. FFN up + ReLU -> hid bf16 [4096,4096]
    gemm256_kernel<1><<<dim3(4096/256, 4096/256, 1), 512, 0, stream>>>(
        out1b, 1024, W1t, 1024, hid, 4096, 1024, b1, nullptr, 1, 0, 0, 0);
    // 9. FFN down, split-K8 -> bf16 partials wpart[z][4096][1024]
    gemm256_kernel<1><<<dim3(1024/256, 4096/256, 8), 512, 0, stream>>>(
        hid, 4096, W2t, 4096, wpart, 1024, 512, nullptr, nullptr, 0,
        512, 512, (long)4096*1024);
    // 10. norm2 fused: sum 8 partials + b2 + out1 resid -> norm -> out
    norm2_fused_kernel<<<dim3(BT_), 256, 0, stream>>>(
        wpart, (long)4096*1024, b2, out1f, out);
}